// Round 7
// baseline (382.422 us; speedup 1.0000x reference)
//
#include <hip/hip_runtime.h>

// GP_36206574305645: out[b,d,n] = sum_m softmax_m(sim[b,n,m]) * f[m,d]
//   b=4, hw=4096, d=64. sim fp32 268 MB read-once.
// R7 probe (solid, OH-independent): sim stream alone = 54.9us = 4.9 TB/s.
// ACCOUNTING CRISIS after R9: with OH=255, R8/R9 imply NT cost +27us; with
//   OH=295 (extra ~50us of reset-dispatch launch gaps), NT ~neutral and all
//   kernels since R3 have been ~70-90us (explaining the 371/376/375 plateau
//   across structurally different kernels). Worlds demand different plans.
// R10 (single-variable A/B): R9 with sim staging aux 2->0 (NT revert) ONLY.
//   Pre-committed: 340-352 => NT was the regression (OH~255, world B);
//   370-378 => NT neutral (OH~295, world A; kernel near floor).
// Structure (R8/R9, passing): 8 waves x 16 n-rows = 128 rows/block, one
//   512-m slice; ftl staged once frag-ordered (64 KB, one barrier); sim
//   wave-private 4-chunk LDS ring via global_load_lds(16B), counted
//   vmcnt(6), zero main-loop barriers; lane-linear ds_reads (0 conflicts);
//   MS=8 softmax split -> P/S partials + combine kernel. Single-pass
//   softmax, no max-subtraction (sim~N(0,1), exp<=~500, f16-safe).

typedef _Float16 f16;
typedef f16 f16x8 __attribute__((ext_vector_type(8)));
typedef float f32x4 __attribute__((ext_vector_type(4)));

static constexpr int HW  = 4096;
static constexpr int ND  = 64;
static constexpr int MS  = 8;        // m-slices (softmax split)
static constexpr int MSL = HW / MS;  // 512 m per slice

#define GLD16(gp, lp) __builtin_amdgcn_global_load_lds(                        \
    (const __attribute__((address_space(1))) void*)(gp),                       \
    (__attribute__((address_space(3))) void*)(lp), 16, 0, 0)

// ---------------------------------------------------------------- kernel A --
__global__ __launch_bounds__(256) void posenc_f16(
    const float* __restrict__ cw, const float* __restrict__ cb,
    f16* __restrict__ ft)
{
    int g = blockIdx.x * 256 + threadIdx.x;      // 0 .. 64*4096-1
    int d = g >> 12;
    int m = g & 4095;
    int i = m >> 6;
    int j = m & 63;
    float gx = (float)(2 * j - 63) * (1.0f / 64.0f);
    float gy = (float)(2 * i - 63) * (1.0f / 64.0f);
    float proj = cw[2 * d] * gx + cw[2 * d + 1] * gy + cb[d];
    float v = cosf(25.132741228718345f * proj);  // 8*pi
    ft[(size_t)d * HW + m] = (f16)v;
}

// ---------------------------------------------------------------- kernel B --
// Fragment-ordered LDS (per-lane global src, linear LDS dest):
//   ftl[(st*4+u)*512 + lane*8]  <- ft row u*16+(lane&15), k=st*32+(lane>>4)*8
//   simw[wv][(ch&3)*512 + h*256 + lane*4] <- sim row nr+(lane&15),
//                                            m=ch*32+(lane>>4)*8+h*4
// A-frag (lane c,q): k=q*8+j ; B-frag: row u*16+c, k=q*8+j ; C/D: col=c,
// row(n)=q*4+reg (verified layout, passing since R3).
__global__ __launch_bounds__(512) void gp_part(
    const float* __restrict__ sim, const f16* __restrict__ ft,
    float* __restrict__ P, float* __restrict__ S)
{
    const int bb   = blockIdx.x >> 8;          // batch
    const int ms   = (blockIdx.x >> 5) & 7;    // m-slice
    const int ng   = blockIdx.x & 31;          // 128-row n-group
    const int tid  = threadIdx.x;
    const int wv   = tid >> 6;
    const int lane = tid & 63;
    const int c    = lane & 15;
    const int q    = lane >> 4;

    __shared__ f16   ftl[64 * 512];            // 64 KB, frag-ordered
    __shared__ float simw[8][4 * 512];         // 64 KB, per-wave 4-chunk ring

    const int mb = ms * MSL;
    const int nr = ng * 128 + wv * 16;

    const float* ssrc = sim + (size_t)bb * HW * HW + (size_t)(nr + c) * HW
                            + mb + q * 8;

    f32x4 acc[4];
    #pragma unroll
    for (int u = 0; u < 4; u++)
        acc[u] = (f32x4){0.f, 0.f, 0.f, 0.f};
    float ps = 0.f;

    auto stage_sim = [&](int ch) {
        const float* g = ssrc + ch * 32;
        float* l = &simw[wv][(ch & 3) * 512];
        GLD16(g,     l);          // h=0: floats q*8+0..3 of 16 rows
        GLD16(g + 4, l + 256);    // h=1: floats q*8+4..7
    };

    // ---- prologue: ft (once, 8 instr/wave) + sim chunks 0..3; one barrier
    #pragma unroll
    for (int r = 0; r < 8; ++r) {
        int p  = r * 8 + wv;
        int st = p >> 2, u = p & 3;
        GLD16(ft + (size_t)(u * 16 + c) * HW + mb + st * 32 + q * 8,
              &ftl[(st * 4 + u) * 512]);
    }
    #pragma unroll
    for (int ch = 0; ch < 4; ++ch)
        stage_sim(ch);
    __syncthreads();              // drains vmcnt(0): ft + chunks 0..3 resident

    auto body = [&](int ch) {
        const float* lw = &simw[wv][(ch & 3) * 512];
        f32x4 s0 = *(const f32x4*)(lw + lane * 4);
        f32x4 s1 = *(const f32x4*)(lw + 256 + lane * 4);
        float p0 = __expf(s0[0]); float p1 = __expf(s0[1]);
        float p2 = __expf(s0[2]); float p3 = __expf(s0[3]);
        float p4 = __expf(s1[0]); float p5 = __expf(s1[1]);
        float p6 = __expf(s1[2]); float p7 = __expf(s1[3]);
        ps += ((p0 + p1) + (p2 + p3)) + ((p4 + p5) + (p6 + p7));
        f16x8 a;
        a[0] = (f16)p0; a[1] = (f16)p1; a[2] = (f16)p2; a[3] = (f16)p3;
        a[4] = (f16)p4; a[5] = (f16)p5; a[6] = (f16)p6; a[7] = (f16)p7;
        const f16* fb = &ftl[ch * 2048 + lane * 8];
        f16x8 b0 = *(const f16x8*)(fb);
        f16x8 b1 = *(const f16x8*)(fb + 512);
        f16x8 b2 = *(const f16x8*)(fb + 1024);
        f16x8 b3 = *(const f16x8*)(fb + 1536);
        acc[0] = __builtin_amdgcn_mfma_f32_16x16x32_f16(a, b0, acc[0], 0, 0, 0);
        acc[1] = __builtin_amdgcn_mfma_f32_16x16x32_f16(a, b1, acc[1], 0, 0, 0);
        acc[2] = __builtin_amdgcn_mfma_f32_16x16x32_f16(a, b2, acc[2], 0, 0, 0);
        acc[3] = __builtin_amdgcn_mfma_f32_16x16x32_f16(a, b3, acc[3], 0, 0, 0);
    };

    // ---- main loop: no barriers; steady state 8 loads (4 chunks) in flight.
    // vmcnt(6) => current chunk's 2 loads done. lgkmcnt(0) before re-staging
    // the ring slot guarantees our ds_reads of that slot retired (WAR).
    for (int ch = 0; ch < 13; ++ch) {
        asm volatile("s_waitcnt vmcnt(6)" ::: "memory");
        body(ch);
        if (ch < 12) {
            asm volatile("s_waitcnt lgkmcnt(0)" ::: "memory");
            stage_sim(ch + 4);
        }
    }
    asm volatile("s_waitcnt vmcnt(4)" ::: "memory"); body(13);
    asm volatile("s_waitcnt vmcnt(2)" ::: "memory"); body(14);
    asm volatile("s_waitcnt vmcnt(0)" ::: "memory"); body(15);

    // ---- epilogue: slice row-sums + unnormalized partials ----
    ps += __shfl_xor(ps, 16, 64);
    ps += __shfl_xor(ps, 32, 64);                 // full row-c sum over slice
    if (q == 0)
        S[(size_t)(ms * 4 + bb) * HW + nr + c] = ps;

    #pragma unroll
    for (int u = 0; u < 4; u++)
        *(f32x4*)(P + ((size_t)(ms * 4 + bb) * ND + u * 16 + c) * HW
                  + nr + q * 4) = acc[u];
}

// ---------------------------------------------------------------- kernel C --
// out[b][d][n] = sum_ms P[ms][b][d][n] / sum_ms S[ms][b][n]
// 1,048,576 outputs / 4 per thread = 1024 blocks x 256 threads.
__global__ __launch_bounds__(256) void gp_combine(
    const float* __restrict__ P, const float* __restrict__ S,
    float* __restrict__ out)
{
    int g  = blockIdx.x * 256 + threadIdx.x;   // 0 .. 262143
    int n4 = (g & 1023) << 2;
    int bd = g >> 10;                          // b*64 + d, 0..255
    int b  = bd >> 6;
    int d  = bd & 63;

    f32x4 a = (f32x4){0.f, 0.f, 0.f, 0.f};
    f32x4 s = (f32x4){0.f, 0.f, 0.f, 0.f};
    #pragma unroll
    for (int m = 0; m < MS; m++) {
        a += *(const f32x4*)(P + ((size_t)(m * 4 + b) * ND + d) * HW + n4);
        s += *(const f32x4*)(S + (size_t)(m * 4 + b) * HW + n4);
    }
    f32x4 o;
    o[0] = a[0] / s[0]; o[1] = a[1] / s[1];
    o[2] = a[2] / s[2]; o[3] = a[3] / s[3];
    *(f32x4*)(out + (size_t)bd * HW + n4) = o;
}

extern "C" void kernel_launch(void* const* d_in, const int* in_sizes, int n_in,
                              void* d_out, int out_size, void* d_ws, size_t ws_size,
                              hipStream_t stream) {
    (void)in_sizes; (void)n_in; (void)out_size; (void)ws_size;
    const float* sim = (const float*)d_in[0];   // [4, 4096, 4096] fp32
    const float* cw  = (const float*)d_in[1];   // [64, 2] fp32
    const float* cb  = (const float*)d_in[2];   // [64] fp32
    float* out = (float*)d_out;                 // [4, 64, 64, 64] fp32

    // workspace: ft 512 KB @0 ; S 512 KB @512K ; P 32 MB @1M
    f16*   ft = (f16*)d_ws;
    float* S  = (float*)((char*)d_ws + (512 << 10));
    float* P  = (float*)((char*)d_ws + (1 << 20));

    posenc_f16<<<(ND * HW) / 256, 256, 0, stream>>>(cw, cb, ft);
    gp_part<<<1024, 512, 0, stream>>>(sim, ft, P, S);
    gp_combine<<<1024, 256, 0, stream>>>(P, S, out);
}

// Round 8
// 373.967 us; speedup vs baseline: 1.0226x; 1.0226x over previous
//
#include <hip/hip_runtime.h>

// GP_36206574305645: out[b,d,n] = sum_m softmax_m(sim[b,n,m]) * f[m,d]
//   b=4, hw=4096, d=64. sim fp32 268 MB read-once.
// SESSION MODEL (settled R10): dur_us = OH(~306us, harness: poison fill
//   ~160 + input restore + reset dispatch gaps) + kernel chain. R8/R10
//   no-NT pair => gp_part ~66us vs 54.9us probe floor (R7: exact sim
//   stream = 4.9 TB/s). R3's chain was already ~65us: the 371-387 plateau
//   was near-floor kernels + /-8us noise. ft is 512KB = always L3-resident
//   (L3 256MB) -- the early "ft evicted" theory was wrong.
// Chain budget: sim 55 + P/S round-trip ~6 + combine ~4 + posenc ~2.
// R11: (a) NT sim staging restored (R9 = 374.9, best post-R3; stream-once
//   data shouldn't thrash L2); (b) P partials stored f16: values bounded
//   ~1e3 << 65504, f16 rel err 5e-4 adds in quadrature to existing ~1e-3
//   -> safely under 4.9e-3 threshold. P traffic 32MB->16MB (-16MB write
//   in gp_part, -16MB read in combine, ~-6us).
//   Predict 366-372, absmax ~1.5-2.5e-3. If >=374: noise-locked, declare.
// Structure (R8-R10, passing): 8 waves x 16 n-rows = 128 rows/block, one
//   512-m slice; ftl staged once frag-ordered (64 KB, one barrier); sim
//   wave-private 4-chunk LDS ring via global_load_lds(16B), counted
//   vmcnt(6), zero main-loop barriers; lane-linear ds_reads (0 conflicts);
//   MS=8 softmax split -> P(f16)/S partials + combine kernel. Single-pass
//   softmax, no max-subtraction (sim~N(0,1), exp<=~500, f16-safe).

typedef _Float16 f16;
typedef f16 f16x4 __attribute__((ext_vector_type(4)));
typedef f16 f16x8 __attribute__((ext_vector_type(8)));
typedef float f32x4 __attribute__((ext_vector_type(4)));

static constexpr int HW  = 4096;
static constexpr int ND  = 64;
static constexpr int MS  = 8;        // m-slices (softmax split)
static constexpr int MSL = HW / MS;  // 512 m per slice

// normal cache policy (ft: keep cached)
#define GLD16(gp, lp) __builtin_amdgcn_global_load_lds(                        \
    (const __attribute__((address_space(1))) void*)(gp),                       \
    (__attribute__((address_space(3))) void*)(lp), 16, 0, 0)
// non-temporal (sim: stream-once, don't pollute L2)
#define GLD16NT(gp, lp) __builtin_amdgcn_global_load_lds(                      \
    (const __attribute__((address_space(1))) void*)(gp),                       \
    (__attribute__((address_space(3))) void*)(lp), 16, 0, 2)

// ---------------------------------------------------------------- kernel A --
__global__ __launch_bounds__(256) void posenc_f16(
    const float* __restrict__ cw, const float* __restrict__ cb,
    f16* __restrict__ ft)
{
    int g = blockIdx.x * 256 + threadIdx.x;      // 0 .. 64*4096-1
    int d = g >> 12;
    int m = g & 4095;
    int i = m >> 6;
    int j = m & 63;
    float gx = (float)(2 * j - 63) * (1.0f / 64.0f);
    float gy = (float)(2 * i - 63) * (1.0f / 64.0f);
    float proj = cw[2 * d] * gx + cw[2 * d + 1] * gy + cb[d];
    float v = cosf(25.132741228718345f * proj);  // 8*pi
    ft[(size_t)d * HW + m] = (f16)v;
}

// ---------------------------------------------------------------- kernel B --
// Fragment-ordered LDS (per-lane global src, linear LDS dest):
//   ftl[(st*4+u)*512 + lane*8]  <- ft row u*16+(lane&15), k=st*32+(lane>>4)*8
//   simw[wv][(ch&3)*512 + h*256 + lane*4] <- sim row nr+(lane&15),
//                                            m=ch*32+(lane>>4)*8+h*4
// A-frag (lane c,q): k=q*8+j ; B-frag: row u*16+c, k=q*8+j ; C/D: col=c,
// row(n)=q*4+reg (verified layout, passing since R3).
__global__ __launch_bounds__(512) void gp_part(
    const float* __restrict__ sim, const f16* __restrict__ ft,
    f16* __restrict__ P, float* __restrict__ S)
{
    const int bb   = blockIdx.x >> 8;          // batch
    const int ms   = (blockIdx.x >> 5) & 7;    // m-slice
    const int ng   = blockIdx.x & 31;          // 128-row n-group
    const int tid  = threadIdx.x;
    const int wv   = tid >> 6;
    const int lane = tid & 63;
    const int c    = lane & 15;
    const int q    = lane >> 4;

    __shared__ f16   ftl[64 * 512];            // 64 KB, frag-ordered
    __shared__ float simw[8][4 * 512];         // 64 KB, per-wave 4-chunk ring

    const int mb = ms * MSL;
    const int nr = ng * 128 + wv * 16;

    const float* ssrc = sim + (size_t)bb * HW * HW + (size_t)(nr + c) * HW
                            + mb + q * 8;

    f32x4 acc[4];
    #pragma unroll
    for (int u = 0; u < 4; u++)
        acc[u] = (f32x4){0.f, 0.f, 0.f, 0.f};
    float ps = 0.f;

    auto stage_sim = [&](int ch) {
        const float* g = ssrc + ch * 32;
        float* l = &simw[wv][(ch & 3) * 512];
        GLD16NT(g,     l);        // h=0: floats q*8+0..3 of 16 rows
        GLD16NT(g + 4, l + 256);  // h=1: floats q*8+4..7
    };

    // ---- prologue: ft (once, 8 instr/wave) + sim chunks 0..3; one barrier
    #pragma unroll
    for (int r = 0; r < 8; ++r) {
        int p  = r * 8 + wv;
        int st = p >> 2, u = p & 3;
        GLD16(ft + (size_t)(u * 16 + c) * HW + mb + st * 32 + q * 8,
              &ftl[(st * 4 + u) * 512]);
    }
    #pragma unroll
    for (int ch = 0; ch < 4; ++ch)
        stage_sim(ch);
    __syncthreads();              // drains vmcnt(0): ft + chunks 0..3 resident

    auto body = [&](int ch) {
        const float* lw = &simw[wv][(ch & 3) * 512];
        f32x4 s0 = *(const f32x4*)(lw + lane * 4);
        f32x4 s1 = *(const f32x4*)(lw + 256 + lane * 4);
        float p0 = __expf(s0[0]); float p1 = __expf(s0[1]);
        float p2 = __expf(s0[2]); float p3 = __expf(s0[3]);
        float p4 = __expf(s1[0]); float p5 = __expf(s1[1]);
        float p6 = __expf(s1[2]); float p7 = __expf(s1[3]);
        ps += ((p0 + p1) + (p2 + p3)) + ((p4 + p5) + (p6 + p7));
        f16x8 a;
        a[0] = (f16)p0; a[1] = (f16)p1; a[2] = (f16)p2; a[3] = (f16)p3;
        a[4] = (f16)p4; a[5] = (f16)p5; a[6] = (f16)p6; a[7] = (f16)p7;
        const f16* fb = &ftl[ch * 2048 + lane * 8];
        f16x8 b0 = *(const f16x8*)(fb);
        f16x8 b1 = *(const f16x8*)(fb + 512);
        f16x8 b2 = *(const f16x8*)(fb + 1024);
        f16x8 b3 = *(const f16x8*)(fb + 1536);
        acc[0] = __builtin_amdgcn_mfma_f32_16x16x32_f16(a, b0, acc[0], 0, 0, 0);
        acc[1] = __builtin_amdgcn_mfma_f32_16x16x32_f16(a, b1, acc[1], 0, 0, 0);
        acc[2] = __builtin_amdgcn_mfma_f32_16x16x32_f16(a, b2, acc[2], 0, 0, 0);
        acc[3] = __builtin_amdgcn_mfma_f32_16x16x32_f16(a, b3, acc[3], 0, 0, 0);
    };

    // ---- main loop: no barriers; steady state 8 loads (4 chunks) in flight.
    // vmcnt(6) => current chunk's 2 loads done. lgkmcnt(0) before re-staging
    // the ring slot guarantees our ds_reads of that slot retired (WAR).
    for (int ch = 0; ch < 13; ++ch) {
        asm volatile("s_waitcnt vmcnt(6)" ::: "memory");
        body(ch);
        if (ch < 12) {
            asm volatile("s_waitcnt lgkmcnt(0)" ::: "memory");
            stage_sim(ch + 4);
        }
    }
    asm volatile("s_waitcnt vmcnt(4)" ::: "memory"); body(13);
    asm volatile("s_waitcnt vmcnt(2)" ::: "memory"); body(14);
    asm volatile("s_waitcnt vmcnt(0)" ::: "memory"); body(15);

    // ---- epilogue: slice row-sums + unnormalized f16 partials ----
    ps += __shfl_xor(ps, 16, 64);
    ps += __shfl_xor(ps, 32, 64);                 // full row-c sum over slice
    if (q == 0)
        S[(size_t)(ms * 4 + bb) * HW + nr + c] = ps;

    #pragma unroll
    for (int u = 0; u < 4; u++) {
        f16x4 h;
        h[0] = (f16)acc[u][0]; h[1] = (f16)acc[u][1];
        h[2] = (f16)acc[u][2]; h[3] = (f16)acc[u][3];
        *(f16x4*)(P + ((size_t)(ms * 4 + bb) * ND + u * 16 + c) * HW
                  + nr + q * 4) = h;
    }
}

// ---------------------------------------------------------------- kernel C --
// out[b][d][n] = sum_ms P[ms][b][d][n] / sum_ms S[ms][b][n]
// 1,048,576 outputs / 4 per thread = 1024 blocks x 256 threads.
__global__ __launch_bounds__(256) void gp_combine(
    const f16* __restrict__ P, const float* __restrict__ S,
    float* __restrict__ out)
{
    int g  = blockIdx.x * 256 + threadIdx.x;   // 0 .. 262143
    int n4 = (g & 1023) << 2;
    int bd = g >> 10;                          // b*64 + d, 0..255
    int b  = bd >> 6;
    int d  = bd & 63;

    f32x4 a = (f32x4){0.f, 0.f, 0.f, 0.f};
    f32x4 s = (f32x4){0.f, 0.f, 0.f, 0.f};
    #pragma unroll
    for (int m = 0; m < MS; m++) {
        f16x4 p = *(const f16x4*)(P + ((size_t)(m * 4 + b) * ND + d) * HW + n4);
        a[0] += (float)p[0]; a[1] += (float)p[1];
        a[2] += (float)p[2]; a[3] += (float)p[3];
        s += *(const f32x4*)(S + (size_t)(m * 4 + b) * HW + n4);
    }
    f32x4 o;
    o[0] = a[0] / s[0]; o[1] = a[1] / s[1];
    o[2] = a[2] / s[2]; o[3] = a[3] / s[3];
    *(f32x4*)(out + (size_t)bd * HW + n4) = o;
}

extern "C" void kernel_launch(void* const* d_in, const int* in_sizes, int n_in,
                              void* d_out, int out_size, void* d_ws, size_t ws_size,
                              hipStream_t stream) {
    (void)in_sizes; (void)n_in; (void)out_size; (void)ws_size;
    const float* sim = (const float*)d_in[0];   // [4, 4096, 4096] fp32
    const float* cw  = (const float*)d_in[1];   // [64, 2] fp32
    const float* cb  = (const float*)d_in[2];   // [64] fp32
    float* out = (float*)d_out;                 // [4, 64, 64, 64] fp32

    // workspace: ft 512 KB @0 ; S 512 KB @512K ; P(f16) 16 MB @1M
    f16*   ft = (f16*)d_ws;
    float* S  = (float*)((char*)d_ws + (512 << 10));
    f16*   P  = (f16*)((char*)d_ws + (1 << 20));

    posenc_f16<<<(ND * HW) / 256, 256, 0, stream>>>(cw, cb, ft);
    gp_part<<<1024, 512, 0, stream>>>(sim, ft, P, S);
    gp_combine<<<1024, 256, 0, stream>>>(P, S, out);
}